// Round 6
// baseline (693.710 us; speedup 1.0000x reference)
//
#include <hip/hip_runtime.h>
#include <cstdint>
#include <cstddef>

typedef unsigned short u16;
typedef __bf16 bf16x8 __attribute__((ext_vector_type(8)));
typedef float f32x4 __attribute__((ext_vector_type(4)));

// ---------- helpers ----------
__device__ __forceinline__ u16 f2bf(float f) {            // round-to-nearest-even
  unsigned u = __float_as_uint(f);
  u += 0x7fffu + ((u >> 16) & 1u);
  return (u16)(u >> 16);
}

__device__ __forceinline__ float block_sum(float v, float* sbuf, int tid) {
#pragma unroll
  for (int off = 1; off < 64; off <<= 1) v += __shfl_xor(v, off, 64);
  if ((tid & 63) == 0) sbuf[tid >> 6] = v;
  __syncthreads();
  v = sbuf[0] + sbuf[1] + sbuf[2] + sbuf[3];
  __syncthreads();
  return v;
}

// async global->LDS, 16B per lane; LDS dest = wave-uniform base + lane*16.
__device__ __forceinline__ void gld16(const void* g, void* l) {
  __builtin_amdgcn_global_load_lds((const __attribute__((address_space(1))) void*)g,
                                   (__attribute__((address_space(3))) void*)l,
                                   16, 0, 0);
}

// Tiled K layout: kt[z][tile][c=d/8][t=0..127][j=d%8]  (16KB/tile, MFMA B-frag image)
// Tiled V layout: vt[z][tile][tc=t/8][d=0..63][j=t%8]  (16KB/tile)

// ---------- big-grid NT GEMM (128x128 tile, BK=32, gld16 staging) ----------
// M=4096. mode 1: QKV -> qh(out0, *0.125)/kt(out1)/vt(out2)
//         mode 2: bf16 gelu(acc+bias) -> out0 row-major ld N
//         mode 3: KV  -> kt(out1)/vt(out2)
__global__ __launch_bounds__(256) void gemm_nt(
    const u16* __restrict__ A, const u16* __restrict__ B,
    const float* __restrict__ bias,
    void* __restrict__ out0, void* __restrict__ out1, void* __restrict__ out2,
    int N, int K, int mode)
{
  __shared__ __align__(16) u16 As[128 * 32];
  __shared__ __align__(16) u16 Bs[128 * 32];
  const int tid = threadIdx.x;
  const int m0 = blockIdx.y * 128, n0 = blockIdx.x * 128;
  const int lane = tid & 63, wave = tid >> 6;
  const int l15 = lane & 15, g = (lane >> 4) & 3;
  const int wm = (wave >> 1) * 64, wn = (wave & 1) * 64;

  const int c0 = tid, c1 = tid + 256;
  const int ar0 = c0 >> 2, ak0 = (c0 & 3) * 8;
  const int ar1 = c1 >> 2, ak1 = (c1 & 3) * 8;
  const size_t aoff0 = (size_t)(m0 + ar0) * K + ak0;
  const size_t aoff1 = (size_t)(m0 + ar1) * K + ak1;
  const size_t boff0 = (size_t)(n0 + ar0) * K + ak0;
  const size_t boff1 = (size_t)(n0 + ar1) * K + ak1;

  f32x4 acc[4][4] = {};

  for (int k0 = 0; k0 < K; k0 += 32) {
    gld16(A + aoff0 + k0, As + (size_t)c0 * 8);
    gld16(A + aoff1 + k0, As + (size_t)c1 * 8);
    gld16(B + boff0 + k0, Bs + (size_t)c0 * 8);
    gld16(B + boff1 + k0, Bs + (size_t)c1 * 8);
    __syncthreads();
    bf16x8 af[4], bg[4];
#pragma unroll
    for (int i = 0; i < 4; i++) {
      af[i] = *(const bf16x8*)(As + (wm + i * 16 + l15) * 32 + g * 8);
      bg[i] = *(const bf16x8*)(Bs + (wn + i * 16 + l15) * 32 + g * 8);
    }
#pragma unroll
    for (int i = 0; i < 4; i++)
#pragma unroll
      for (int j = 0; j < 4; j++)
        acc[i][j] = __builtin_amdgcn_mfma_f32_16x16x32_bf16(af[i], bg[j], acc[i][j], 0, 0, 0);
    __syncthreads();
  }

#pragma unroll
  for (int i = 0; i < 4; i++) {
#pragma unroll
    for (int j = 0; j < 4; j++) {
      const int col = n0 + wn + j * 16 + l15;
      const int sec = (n0 + wn + j * 16) >> 10;        // wave-uniform section
#pragma unroll
      for (int r = 0; r < 4; r++) {
        const int gm = m0 + wm + i * 16 + g * 4 + r;
        float v = acc[i][j][r] + bias[col];
        if (mode == 2) {
          v = 0.5f * v * (1.0f + erff(v * 0.70710678118654752f));
          ((u16*)out0)[(size_t)gm * N + col] = f2bf(v);
        } else {
          const int tgt = (mode == 1) ? sec : sec + 1;
          const int cl = col & 1023, h = cl >> 6, d = cl & 63;
          const int z = (gm >> 10) * 16 + h, s = gm & 1023;
          if (tgt == 0)
            ((u16*)out0)[((size_t)z * 1024 + s) * 64 + d] = f2bf(v * 0.125f);
          else if (tgt == 1)
            ((u16*)out1)[((((size_t)z * 8 + (s >> 7)) * 8 + (d >> 3)) * 128 + (s & 127)) * 8 + (d & 7)] = f2bf(v);
          else
            ((u16*)out2)[((size_t)z * 8 + (s >> 7)) * 8192 + (((s >> 3) & 15) * 64 + d) * 8 + (s & 7)] = f2bf(v);
        }
      }
    }
  }
}

// ---------- split-K NT GEMM (M=4096, N=1024; fp32 partials [z][4096][1024]) ----------
__global__ __launch_bounds__(256) void gemm_splitk(
    const u16* __restrict__ A, const u16* __restrict__ B,
    float* __restrict__ part, int K, int Klen)
{
  __shared__ __align__(16) u16 As[128 * 32];
  __shared__ __align__(16) u16 Bs[128 * 32];
  const int tid = threadIdx.x;
  const int m0 = blockIdx.y * 128, n0 = blockIdx.x * 128;
  const int kstart = blockIdx.z * Klen;
  float* outP = part + (size_t)blockIdx.z * (4096ULL * 1024);
  const int lane = tid & 63, wave = tid >> 6;
  const int l15 = lane & 15, g = (lane >> 4) & 3;
  const int wm = (wave >> 1) * 64, wn = (wave & 1) * 64;

  const int c0 = tid, c1 = tid + 256;
  const int ar0 = c0 >> 2, ak0 = (c0 & 3) * 8;
  const int ar1 = c1 >> 2, ak1 = (c1 & 3) * 8;
  const size_t aoff0 = (size_t)(m0 + ar0) * K + ak0;
  const size_t aoff1 = (size_t)(m0 + ar1) * K + ak1;
  const size_t boff0 = (size_t)(n0 + ar0) * K + ak0;
  const size_t boff1 = (size_t)(n0 + ar1) * K + ak1;

  f32x4 acc[4][4] = {};

  for (int k0 = kstart; k0 < kstart + Klen; k0 += 32) {
    gld16(A + aoff0 + k0, As + (size_t)c0 * 8);
    gld16(A + aoff1 + k0, As + (size_t)c1 * 8);
    gld16(B + boff0 + k0, Bs + (size_t)c0 * 8);
    gld16(B + boff1 + k0, Bs + (size_t)c1 * 8);
    __syncthreads();
    bf16x8 af[4], bg[4];
#pragma unroll
    for (int i = 0; i < 4; i++) {
      af[i] = *(const bf16x8*)(As + (wm + i * 16 + l15) * 32 + g * 8);
      bg[i] = *(const bf16x8*)(Bs + (wn + i * 16 + l15) * 32 + g * 8);
    }
#pragma unroll
    for (int i = 0; i < 4; i++)
#pragma unroll
      for (int j = 0; j < 4; j++)
        acc[i][j] = __builtin_amdgcn_mfma_f32_16x16x32_bf16(af[i], bg[j], acc[i][j], 0, 0, 0);
    __syncthreads();
  }

#pragma unroll
  for (int i = 0; i < 4; i++)
#pragma unroll
    for (int j = 0; j < 4; j++) {
      const int col = n0 + wn + j * 16 + l15;
#pragma unroll
      for (int r = 0; r < 4; r++) {
        const int gm = m0 + wm + i * 16 + g * 4 + r;
        outP[(size_t)gm * 1024 + col] = acc[i][j][r];
      }
    }
}

// ---------- flash attention v3 (R5, proven) ----------
__global__ __launch_bounds__(256, 2) void flash_attn(
    const u16* __restrict__ qh, const u16* __restrict__ kt, const u16* __restrict__ vt,
    const float* __restrict__ emask, u16* __restrict__ ctx, int causal)
{
  __shared__ __align__(16) u16 sK[8192];
  __shared__ __align__(16) u16 sV[8192];
  __shared__ __align__(16) u16 sP[128 * 72];

  const int tid = threadIdx.x, lane = tid & 63, wave = tid >> 6;
  const int l15 = lane & 15, g = (lane >> 4) & 3;
  const int z = blockIdx.y, b = z >> 4, h = z & 15;
  const int m0 = blockIdx.x * 128;
  const int r0 = wave * 32;

  bf16x8 qf[2][2];
  {
    const u16* qz = qh + ((size_t)z * 1024 + m0 + r0 + l15) * 64 + g * 8;
#pragma unroll
    for (int i2 = 0; i2 < 2; ++i2)
#pragma unroll
      for (int kc = 0; kc < 2; ++kc)
        qf[i2][kc] = *(const bf16x8*)(qz + (size_t)i2 * 16 * 64 + kc * 32);
  }

  float m_i[2][4], l_i[2][4];
#pragma unroll
  for (int i2 = 0; i2 < 2; ++i2)
#pragma unroll
    for (int r = 0; r < 4; ++r) { m_i[i2][r] = -1.0e30f; l_i[i2][r] = 0.0f; }

  f32x4 o[2][4] = {};
  const int tmax = causal ? m0 : 896;

  for (int t0 = 0; t0 <= tmax; t0 += 128) {
    const u16* ktile = kt + ((size_t)z * 8 + (t0 >> 7)) * 8192;
    const u16* vtile = vt + ((size_t)z * 8 + (t0 >> 7)) * 8192;
    __syncthreads();
#pragma unroll
    for (int i = 0; i < 4; ++i) {
      const int off = (wave * 4 + i) * 512 + lane * 8;
      gld16(ktile + off, sK + off);
      gld16(vtile + off, sV + off);
    }
    __syncthreads();

#pragma unroll
    for (int ci = 0; ci < 2; ++ci) {
      if (causal && t0 == m0 && ci * 64 > r0 + 31) continue;

      f32x4 sa[2][4] = {};
#pragma unroll
      for (int kc = 0; kc < 2; ++kc) {
        bf16x8 bg[4];
#pragma unroll
        for (int jn = 0; jn < 4; ++jn)
          bg[jn] = *(const bf16x8*)(sK + ((kc * 4 + g) * 128 + ci * 64 + jn * 16 + l15) * 8);
#pragma unroll
        for (int i2 = 0; i2 < 2; ++i2)
#pragma unroll
          for (int jn = 0; jn < 4; ++jn)
            sa[i2][jn] = __builtin_amdgcn_mfma_f32_16x16x32_bf16(qf[i2][kc], bg[jn], sa[i2][jn], 0, 0, 0);
      }

      if (causal) {
        if (t0 == m0 && ci * 64 + 63 > r0) {
#pragma unroll
          for (int i2 = 0; i2 < 2; ++i2)
#pragma unroll
            for (int jn = 0; jn < 4; ++jn) {
              const int col = ci * 64 + jn * 16 + l15;
#pragma unroll
              for (int r = 0; r < 4; ++r) {
                const int row = r0 + i2 * 16 + g * 4 + r;
                if (col > row) sa[i2][jn][r] = -3.0e38f;
              }
            }
        }
      } else {
#pragma unroll
        for (int jn = 0; jn < 4; ++jn) {
          const float mv = emask[(size_t)b * 1024 + t0 + ci * 64 + jn * 16 + l15];
#pragma unroll
          for (int i2 = 0; i2 < 2; ++i2)
#pragma unroll
            for (int r = 0; r < 4; ++r) sa[i2][jn][r] += mv;
        }
      }

      float alpha[2][4];
#pragma unroll
      for (int i2 = 0; i2 < 2; ++i2)
#pragma unroll
        for (int r = 0; r < 4; ++r) {
          const int rowl = r0 + i2 * 16 + g * 4 + r;
          float v = fmaxf(fmaxf(sa[i2][0][r], sa[i2][1][r]), fmaxf(sa[i2][2][r], sa[i2][3][r]));
          v = fmaxf(v, __shfl_xor(v, 1, 64));
          v = fmaxf(v, __shfl_xor(v, 2, 64));
          v = fmaxf(v, __shfl_xor(v, 4, 64));
          v = fmaxf(v, __shfl_xor(v, 8, 64));
          const float mo = m_i[i2][r];
          const float mn = fmaxf(mo, v);
          m_i[i2][r] = mn;
          alpha[i2][r] = __expf(mo - mn);
          float s = 0.0f;
#pragma unroll
          for (int jn = 0; jn < 4; ++jn) {
            const float p = __expf(sa[i2][jn][r] - mn);
            s += p;
            sP[rowl * 72 + jn * 16 + l15] = f2bf(p);
          }
          s += __shfl_xor(s, 1, 64);
          s += __shfl_xor(s, 2, 64);
          s += __shfl_xor(s, 4, 64);
          s += __shfl_xor(s, 8, 64);
          l_i[i2][r] = alpha[i2][r] * l_i[i2][r] + s;
        }

#pragma unroll
      for (int i2 = 0; i2 < 2; ++i2)
#pragma unroll
        for (int jn = 0; jn < 4; ++jn)
#pragma unroll
          for (int r = 0; r < 4; ++r)
            o[i2][jn][r] *= alpha[i2][r];

      asm volatile("s_waitcnt lgkmcnt(0)" ::: "memory");
#pragma unroll
      for (int kc2 = 0; kc2 < 2; ++kc2) {
        bf16x8 pa[2], vb[4];
#pragma unroll
        for (int i2 = 0; i2 < 2; ++i2)
          pa[i2] = *(const bf16x8*)(sP + (r0 + i2 * 16 + l15) * 72 + kc2 * 32 + g * 8);
#pragma unroll
        for (int jn = 0; jn < 4; ++jn)
          vb[jn] = *(const bf16x8*)(sV + ((ci * 8 + kc2 * 4 + g) * 64 + jn * 16 + l15) * 8);
#pragma unroll
        for (int i2 = 0; i2 < 2; ++i2)
#pragma unroll
          for (int jn = 0; jn < 4; ++jn)
            o[i2][jn] = __builtin_amdgcn_mfma_f32_16x16x32_bf16(pa[i2], vb[jn], o[i2][jn], 0, 0, 0);
      }
    }
  }

#pragma unroll
  for (int i2 = 0; i2 < 2; ++i2)
#pragma unroll
    for (int r = 0; r < 4; ++r) {
      const float inv = 1.0f / l_i[i2][r];
      const size_t base = ((size_t)(b * 1024 + m0 + r0 + i2 * 16 + g * 4 + r)) * 1024 + h * 64;
#pragma unroll
      for (int jn = 0; jn < 4; ++jn)
        ctx[base + jn * 16 + l15] = f2bf(o[i2][jn][r] * inv);
    }
}

// ---------- mega prep: 7 weight transposes + enc cvt + LN1 in one launch ----------
// blocks [0,16384): wconv tiles; [16384,20480): enc cvt; [20480,24576): LN1
struct PrepArgs {
  const float* w[7]; u16* wt[7]; int K[7]; int N[7]; int cum[7];
  const float* enc; u16* enc_bf;
  const float* hid; const float* ln1w; const float* ln1b; u16* xln;
};
__global__ __launch_bounds__(256) void prep_kernel(PrepArgs a) {
  __shared__ float t[32][33];
  __shared__ float sbuf[4];
  const int bb = blockIdx.x, tid = threadIdx.x;
  if (bb < 16384) {
    int wi = 0;
#pragma unroll
    for (int i = 0; i < 7; ++i) if (bb >= a.cum[i]) wi = i + 1; else break;
    const int base = wi ? a.cum[wi - 1] : 0;
    const int tileIdx = bb - base;
    const int Kd = a.K[wi], Nd = a.N[wi], nx = Nd >> 5;
    const int n0 = (tileIdx % nx) * 32, k0 = (tileIdx / nx) * 32;
    const float* w = a.w[wi]; u16* wt = a.wt[wi];
    const int tx = tid & 31, ty = tid >> 5;
#pragma unroll
    for (int r = ty; r < 32; r += 8) t[r][tx] = w[(size_t)(k0 + r) * Nd + n0 + tx];
    __syncthreads();
#pragma unroll
    for (int r = ty; r < 32; r += 8) wt[(size_t)(n0 + r) * Kd + k0 + tx] = f2bf(t[tx][r]);
  } else if (bb < 20480) {
    const size_t i = ((size_t)(bb - 16384) * 256 + tid) * 4;
    const float4 v = *(const float4*)(a.enc + i);
    ushort4 o; o.x = f2bf(v.x); o.y = f2bf(v.y); o.z = f2bf(v.z); o.w = f2bf(v.w);
    *(ushort4*)(a.enc_bf + i) = o;
  } else {
    const int row = bb - 20480;
    const float4 v = *(const float4*)(a.hid + (size_t)row * 1024 + tid * 4);
    float s = block_sum(v.x + v.y + v.z + v.w, sbuf, tid);
    const float u = s * (1.0f / 1024.0f);
    const float d0 = v.x - u, d1 = v.y - u, d2 = v.z - u, d3 = v.w - u;
    float sq = block_sum(d0 * d0 + d1 * d1 + d2 * d2 + d3 * d3, sbuf, tid);
    const float rstd = rsqrtf(sq * (1.0f / 1024.0f) + 1e-12f);
    const int c = tid * 4;
    ushort4 o;
    o.x = f2bf(a.ln1w[c + 0] * d0 * rstd + a.ln1b[c + 0]);
    o.y = f2bf(a.ln1w[c + 1] * d1 * rstd + a.ln1b[c + 1]);
    o.z = f2bf(a.ln1w[c + 2] * d2 * rstd + a.ln1b[c + 2]);
    o.w = f2bf(a.ln1w[c + 3] * d3 * rstd + a.ln1b[c + 3]);
    *(ushort4*)(a.xln + (size_t)row * 1024 + c) = o;
  }
}

// ---------- 4-way reducers ----------
__device__ __forceinline__ float4 sum4(const float* p, size_t off) {
  const float4 a0 = *(const float4*)(p + off);
  const float4 a1 = *(const float4*)(p + 4194304 + off);
  const float4 a2 = *(const float4*)(p + 8388608 + off);
  const float4 a3 = *(const float4*)(p + 12582912 + off);
  float4 v;
  v.x = (a0.x + a1.x) + (a2.x + a3.x);
  v.y = (a0.y + a1.y) + (a2.y + a3.y);
  v.z = (a0.z + a1.z) + (a2.z + a3.z);
  v.w = (a0.w + a1.w) + (a2.w + a3.w);
  return v;
}

__global__ __launch_bounds__(256) void ln_red4_kernel(
    const float* __restrict__ p, const float* __restrict__ bias,
    const float* __restrict__ res, const float* __restrict__ w,
    const float* __restrict__ b, float* __restrict__ hOut, u16* __restrict__ xln)
{
  __shared__ float sbuf[4];
  const int row = blockIdx.x, tid = threadIdx.x;
  const size_t off = (size_t)row * 1024 + tid * 4;
  const int c = tid * 4;
  float4 v = sum4(p, off);
  const float4 bs = *(const float4*)(bias + c);
  const float4 rs = *(const float4*)(res + off);
  v.x += bs.x + rs.x; v.y += bs.y + rs.y; v.z += bs.z + rs.z; v.w += bs.w + rs.w;
  *(float4*)(hOut + off) = v;
  float s = block_sum(v.x + v.y + v.z + v.w, sbuf, tid);
  const float u = s * (1.0f / 1024.0f);
  const float d0 = v.x - u, d1 = v.y - u, d2 = v.z - u, d3 = v.w - u;
  float sq = block_sum(d0 * d0 + d1 * d1 + d2 * d2 + d3 * d3, sbuf, tid);
  const float rstd = rsqrtf(sq * (1.0f / 1024.0f) + 1e-12f);
  ushort4 o;
  o.x = f2bf(w[c + 0] * d0 * rstd + b[c + 0]);
  o.y = f2bf(w[c + 1] * d1 * rstd + b[c + 1]);
  o.z = f2bf(w[c + 2] * d2 * rstd + b[c + 2]);
  o.w = f2bf(w[c + 3] * d3 * rstd + b[c + 3]);
  *(ushort4*)(xln + off) = o;
}

__global__ __launch_bounds__(256) void reduce_q4_kernel(
    const float* __restrict__ p, const float* __restrict__ bias, u16* __restrict__ qh)
{
  const int m = blockIdx.x, tid = threadIdx.x;
  const size_t off = (size_t)m * 1024 + tid * 4;
  const int n = tid * 4, h = n >> 6, d = n & 63;
  const int b = m >> 10, s = m & 1023;
  float4 v = sum4(p, off);
  const float4 bs = *(const float4*)(bias + n);
  ushort4 o;
  o.x = f2bf((v.x + bs.x) * 0.125f);
  o.y = f2bf((v.y + bs.y) * 0.125f);
  o.z = f2bf((v.z + bs.z) * 0.125f);
  o.w = f2bf((v.w + bs.w) * 0.125f);
  *(ushort4*)(qh + ((size_t)((b * 16 + h) * 1024 + s)) * 64 + d) = o;
}

__global__ __launch_bounds__(256) void reduce_out4_kernel(
    const float* __restrict__ p, const float* __restrict__ bias,
    const float* __restrict__ res, float* __restrict__ out)
{
  const int m = blockIdx.x, tid = threadIdx.x;
  const size_t off = (size_t)m * 1024 + tid * 4;
  const int c = tid * 4;
  float4 v = sum4(p, off);
  const float4 bs = *(const float4*)(bias + c);
  const float4 rs = *(const float4*)(res + off);
  v.x += bs.x + rs.x; v.y += bs.y + rs.y; v.z += bs.z + rs.z; v.w += bs.w + rs.w;
  *(float4*)(out + off) = v;
}

// ---------- workspace layout (bytes) ----------
constexpr size_t MB = 1024ULL * 1024;
constexpr size_t WT_QKV    = 0;            // 6 MB
constexpr size_t WT_ATTN_O = 6 * MB;       // 2
constexpr size_t WT_Q      = 8 * MB;       // 2
constexpr size_t WT_KV     = 10 * MB;      // 4
constexpr size_t WT_CA_O   = 14 * MB;      // 2
constexpr size_t WT_FFN_IN = 16 * MB;      // 8
constexpr size_t WT_FFN_OUT= 24 * MB;      // 8
constexpr size_t ENC_BF    = 32 * MB;      // 8
constexpr size_t XLN       = 40 * MB;      // 8
constexpr size_t QH        = 48 * MB;      // 8   (QH..CTX = 32 MB, reused as ffn_mid)
constexpr size_t KT        = 56 * MB;      // 8
constexpr size_t VT        = 64 * MB;      // 8
constexpr size_t CTX       = 72 * MB;      // 8
constexpr size_t HBUF      = 80 * MB;      // 16 (fp32 residual spine)
constexpr size_t SP        = 96 * MB;      // 64 (4 x 16 MB fp32 partials)
// total 160 MB

extern "C" void kernel_launch(void* const* d_in, const int* in_sizes, int n_in,
                              void* d_out, int out_size, void* d_ws, size_t ws_size,
                              hipStream_t stream) {
  const float* hidden   = (const float*)d_in[0];
  const float* enc      = (const float*)d_in[1];
  const float* encm     = (const float*)d_in[2];
  const float* ln1w = (const float*)d_in[4],  *ln1b = (const float*)d_in[5];
  const float* qkv_w = (const float*)d_in[6], *qkv_b = (const float*)d_in[7];
  const float* attn_o_w = (const float*)d_in[8], *attn_o_b = (const float*)d_in[9];
  const float* ln2w = (const float*)d_in[10], *ln2b = (const float*)d_in[11];
  const float* q_w = (const float*)d_in[12],  *q_b = (const float*)d_in[13];
  const float* kv_w = (const float*)d_in[14], *kv_b = (const float*)d_in[15];
  const float* ca_o_w = (const float*)d_in[16], *ca_o_b = (const float*)d_in[17];
  const float* ln3w = (const float*)d_in[18], *ln3b = (const float*)d_in[19];
  const float* ffn_in_w = (const float*)d_in[20], *ffn_in_b = (const float*)d_in[21];
  const float* ffn_out_w = (const float*)d_in[22], *ffn_out_b = (const float*)d_in[23];

  char* ws = (char*)d_ws;
  u16* wt_qkv    = (u16*)(ws + WT_QKV);
  u16* wt_attn_o = (u16*)(ws + WT_ATTN_O);
  u16* wt_q      = (u16*)(ws + WT_Q);
  u16* wt_kv     = (u16*)(ws + WT_KV);
  u16* wt_ca_o   = (u16*)(ws + WT_CA_O);
  u16* wt_ffn_in = (u16*)(ws + WT_FFN_IN);
  u16* wt_ffn_out= (u16*)(ws + WT_FFN_OUT);
  u16* enc_bf = (u16*)(ws + ENC_BF);
  u16* xln    = (u16*)(ws + XLN);
  u16* qh     = (u16*)(ws + QH);
  u16* kt     = (u16*)(ws + KT);
  u16* vt     = (u16*)(ws + VT);
  u16* ctx    = (u16*)(ws + CTX);
  float* hF   = (float*)(ws + HBUF);
  float* sp   = (float*)(ws + SP);
  u16* ffn_mid = (u16*)(ws + QH);   // 32 MB overlay of QH..CTX (dead during FFN)

  // ---- prep: all weight transposes + enc cvt + LN1, one launch ----
  PrepArgs pa;
  pa.w[0] = qkv_w;    pa.wt[0] = wt_qkv;     pa.K[0] = 1024; pa.N[0] = 3072; pa.cum[0] = 3072;
  pa.w[1] = attn_o_w; pa.wt[1] = wt_attn_o;  pa.K[1] = 1024; pa.N[1] = 1024; pa.cum[1] = 4096;
  pa.w[2] = q_w;      pa.wt[2] = wt_q;       pa.K[2] = 1024; pa.N[2] = 1024; pa.cum[2] = 5120;
  pa.w[3] = kv_w;     pa.wt[3] = wt_kv;      pa.K[3] = 1024; pa.N[3] = 2048; pa.cum[3] = 7168;
  pa.w[4] = ca_o_w;   pa.wt[4] = wt_ca_o;    pa.K[4] = 1024; pa.N[4] = 1024; pa.cum[4] = 8192;
  pa.w[5] = ffn_in_w; pa.wt[5] = wt_ffn_in;  pa.K[5] = 1024; pa.N[5] = 4096; pa.cum[5] = 12288;
  pa.w[6] = ffn_out_w;pa.wt[6] = wt_ffn_out; pa.K[6] = 4096; pa.N[6] = 1024; pa.cum[6] = 16384;
  pa.enc = enc; pa.enc_bf = enc_bf;
  pa.hid = hidden; pa.ln1w = ln1w; pa.ln1b = ln1b; pa.xln = xln;
  prep_kernel<<<24576, 256, 0, stream>>>(pa);

  // ---- self-attention ----
  gemm_nt<<<dim3(24, 32), 256, 0, stream>>>(xln, wt_qkv, qkv_b,
      qh, kt, vt, 3072, 1024, 1);
  flash_attn<<<dim3(8, 64), 256, 0, stream>>>(qh, kt, vt, nullptr, ctx, 1);
  gemm_splitk<<<dim3(8, 32, 4), 256, 0, stream>>>(ctx, wt_attn_o, sp, 1024, 256);
  ln_red4_kernel<<<4096, 256, 0, stream>>>(sp, attn_o_b, hidden, ln2w, ln2b, hF, xln);

  // ---- cross-attention ----
  gemm_splitk<<<dim3(8, 32, 4), 256, 0, stream>>>(xln, wt_q, sp, 1024, 256);
  reduce_q4_kernel<<<4096, 256, 0, stream>>>(sp, q_b, qh);
  gemm_nt<<<dim3(16, 32), 256, 0, stream>>>(enc_bf, wt_kv, kv_b,
      nullptr, kt, vt, 2048, 1024, 3);
  flash_attn<<<dim3(8, 64), 256, 0, stream>>>(qh, kt, vt, encm, ctx, 0);
  gemm_splitk<<<dim3(8, 32, 4), 256, 0, stream>>>(ctx, wt_ca_o, sp, 1024, 256);
  ln_red4_kernel<<<4096, 256, 0, stream>>>(sp, ca_o_b, hF, ln3w, ln3b, hF, xln);

  // ---- FFN ----
  gemm_nt<<<dim3(32, 32), 256, 0, stream>>>(xln, wt_ffn_in, ffn_in_b,
      ffn_mid, nullptr, nullptr, 4096, 1024, 2);
  gemm_splitk<<<dim3(8, 32, 4), 256, 0, stream>>>(ffn_mid, wt_ffn_out, sp, 4096, 1024);
  reduce_out4_kernel<<<4096, 256, 0, stream>>>(sp, ffn_out_b, hF, (float*)d_out);
}

// Round 7
// 602.968 us; speedup vs baseline: 1.1505x; 1.1505x over previous
//
#include <hip/hip_runtime.h>
#include <cstdint>
#include <cstddef>

typedef unsigned short u16;
typedef __bf16 bf16x8 __attribute__((ext_vector_type(8)));
typedef float f32x4 __attribute__((ext_vector_type(4)));

// ---------- helpers ----------
__device__ __forceinline__ u16 f2bf(float f) {            // round-to-nearest-even
  unsigned u = __float_as_uint(f);
  u += 0x7fffu + ((u >> 16) & 1u);
  return (u16)(u >> 16);
}

__device__ __forceinline__ float block_sum(float v, float* sbuf, int tid) {
#pragma unroll
  for (int off = 1; off < 64; off <<= 1) v += __shfl_xor(v, off, 64);
  if ((tid & 63) == 0) sbuf[tid >> 6] = v;
  __syncthreads();
  v = sbuf[0] + sbuf[1] + sbuf[2] + sbuf[3];
  __syncthreads();
  return v;
}

// async global->LDS, 16B per lane; LDS dest = wave-uniform base + lane*16.
__device__ __forceinline__ void gld16(const void* g, void* l) {
  __builtin_amdgcn_global_load_lds((const __attribute__((address_space(1))) void*)g,
                                   (__attribute__((address_space(3))) void*)l,
                                   16, 0, 0);
}

// XCD-aware tile swizzle (requires gridDim.x % 8 == 0). Blocks with the same
// (id mod 8) land on the same XCD under round-robin dispatch; give each XCD a
// contiguous n-tile range so its B-tiles stay L2-resident across all m.
__device__ __forceinline__ void swz(int& bx, int& by) {
  const int gx = gridDim.x, gy = gridDim.y;
  const int id = blockIdx.y * gx + blockIdx.x;
  const int xcd = id & 7, slot = id >> 3;
  bx = xcd * (gx >> 3) + slot / gy;
  by = slot % gy;
}

// Tiled K layout: kt[z][tile][c=d/8][t=0..127][j=d%8]  (16KB/tile, MFMA B-frag image)
// Tiled V layout: vt[z][tile][tc=t/8][d=0..63][j=t%8]  (16KB/tile)

// ---------- GEMM K-loop body (128x128 tile, BK=32, gld16 staging) ----------
#define GEMM_BODY(Aptr, Bptr, Kdim)                                              \
  const int lane = tid & 63, wave = tid >> 6;                                    \
  const int l15 = lane & 15, g = (lane >> 4) & 3;                                \
  const int wm = (wave >> 1) * 64, wn = (wave & 1) * 64;                         \
  const int c0 = tid, c1 = tid + 256;                                            \
  const int ar0 = c0 >> 2, ak0 = (c0 & 3) * 8;                                   \
  const int ar1 = c1 >> 2, ak1 = (c1 & 3) * 8;                                   \
  const size_t aoff0 = (size_t)(m0 + ar0) * Kdim + ak0;                          \
  const size_t aoff1 = (size_t)(m0 + ar1) * Kdim + ak1;                          \
  const size_t boff0 = (size_t)(n0 + ar0) * Kdim + ak0;                          \
  const size_t boff1 = (size_t)(n0 + ar1) * Kdim + ak1;                          \
  f32x4 acc[4][4] = {};                                                          \
  for (int k0 = kstart; k0 < kend; k0 += 32) {                                   \
    gld16(Aptr + aoff0 + k0, As + (size_t)c0 * 8);                               \
    gld16(Aptr + aoff1 + k0, As + (size_t)c1 * 8);                               \
    gld16(Bptr + boff0 + k0, Bs + (size_t)c0 * 8);                               \
    gld16(Bptr + boff1 + k0, Bs + (size_t)c1 * 8);                               \
    __syncthreads();                                                             \
    bf16x8 af[4], bg[4];                                                         \
    _Pragma("unroll")                                                            \
    for (int i = 0; i < 4; i++) {                                                \
      af[i] = *(const bf16x8*)(As + (wm + i * 16 + l15) * 32 + g * 8);           \
      bg[i] = *(const bf16x8*)(Bs + (wn + i * 16 + l15) * 32 + g * 8);           \
    }                                                                            \
    _Pragma("unroll")                                                            \
    for (int i = 0; i < 4; i++)                                                  \
      _Pragma("unroll")                                                          \
      for (int j = 0; j < 4; j++)                                                \
        acc[i][j] = __builtin_amdgcn_mfma_f32_16x16x32_bf16(af[i], bg[j], acc[i][j], 0, 0, 0); \
    __syncthreads();                                                             \
  }

// ---------- GELU GEMM (mode-2 of old gemm_nt, specialized; M=4096) ----------
__global__ __launch_bounds__(256) void gemm_gelu(
    const u16* __restrict__ A, const u16* __restrict__ B,
    const float* __restrict__ bias, u16* __restrict__ out, int N, int K)
{
  __shared__ __align__(16) u16 As[128 * 32];
  __shared__ __align__(16) u16 Bs[128 * 32];
  const int tid = threadIdx.x;
  int bx, by; swz(bx, by);
  const int m0 = by * 128, n0 = bx * 128;
  const int kstart = 0, kend = K;
  GEMM_BODY(A, B, K)

#pragma unroll
  for (int i = 0; i < 4; i++) {
#pragma unroll
    for (int j = 0; j < 4; j++) {
      const int col = n0 + wn + j * 16 + l15;
#pragma unroll
      for (int r = 0; r < 4; r++) {
        const int gm = m0 + wm + i * 16 + g * 4 + r;
        float v = acc[i][j][r] + bias[col];
        v = 0.5f * v * (1.0f + erff(v * 0.70710678118654752f));
        out[(size_t)gm * N + col] = f2bf(v);
      }
    }
  }
}

// ---------- QKV / KV GEMM (direct head-split tiled epilogues; M=4096) ----------
// mode 1: sections q/k/v -> qh(*0.125)/kt/vt.  mode 3: sections k/v -> kt/vt.
__global__ __launch_bounds__(256) void gemm_qkv(
    const u16* __restrict__ A, const u16* __restrict__ B,
    const float* __restrict__ bias,
    u16* __restrict__ qh, u16* __restrict__ kt, u16* __restrict__ vt,
    int K, int mode)
{
  __shared__ __align__(16) u16 As[128 * 32];
  __shared__ __align__(16) u16 Bs[128 * 32];
  const int tid = threadIdx.x;
  int bx, by; swz(bx, by);
  const int m0 = by * 128, n0 = bx * 128;
  const int kstart = 0, kend = K;
  GEMM_BODY(A, B, K)

#pragma unroll
  for (int i = 0; i < 4; i++) {
#pragma unroll
    for (int j = 0; j < 4; j++) {
      const int col = n0 + wn + j * 16 + l15;
      const int sec = (n0 + wn + j * 16) >> 10;          // wave-uniform section
      const int tgt = (mode == 1) ? sec : sec + 1;
#pragma unroll
      for (int r = 0; r < 4; r++) {
        const int gm = m0 + wm + i * 16 + g * 4 + r;
        const float v = acc[i][j][r] + bias[col];
        const int cl = col & 1023, h = cl >> 6, d = cl & 63;
        const int z = (gm >> 10) * 16 + h, s = gm & 1023;
        if (tgt == 0)
          qh[((size_t)z * 1024 + s) * 64 + d] = f2bf(v * 0.125f);
        else if (tgt == 1)
          kt[((((size_t)z * 8 + (s >> 7)) * 8 + (d >> 3)) * 128 + (s & 127)) * 8 + (d & 7)] = f2bf(v);
        else
          vt[((size_t)z * 8 + (s >> 7)) * 8192 + (((s >> 3) & 15) * 64 + d) * 8 + (s & 7)] = f2bf(v);
      }
    }
  }
}

// ---------- split-K NT GEMM (M=4096, N=1024; fp32 partials [z][4096][1024]) ----------
__global__ __launch_bounds__(256) void gemm_splitk(
    const u16* __restrict__ A, const u16* __restrict__ B,
    float* __restrict__ part, int K, int Klen)
{
  __shared__ __align__(16) u16 As[128 * 32];
  __shared__ __align__(16) u16 Bs[128 * 32];
  const int tid = threadIdx.x;
  int bx, by; swz(bx, by);
  const int m0 = by * 128, n0 = bx * 128;
  const int kstart = blockIdx.z * Klen, kend = kstart + Klen;
  float* outP = part + (size_t)blockIdx.z * (4096ULL * 1024);
  GEMM_BODY(A, B, K)

#pragma unroll
  for (int i = 0; i < 4; i++)
#pragma unroll
    for (int j = 0; j < 4; j++) {
      const int col = n0 + wn + j * 16 + l15;
#pragma unroll
      for (int r = 0; r < 4; r++) {
        const int gm = m0 + wm + i * 16 + g * 4 + r;
        outP[(size_t)gm * 1024 + col] = acc[i][j][r];
      }
    }
}

// ---------- flash attention v3 (proven) + head-per-XCD swizzle ----------
__global__ __launch_bounds__(256, 2) void flash_attn(
    const u16* __restrict__ qh, const u16* __restrict__ kt, const u16* __restrict__ vt,
    const float* __restrict__ emask, u16* __restrict__ ctx, int causal)
{
  __shared__ __align__(16) u16 sK[8192];
  __shared__ __align__(16) u16 sV[8192];
  __shared__ __align__(16) u16 sP[128 * 72];

  const int tid = threadIdx.x, lane = tid & 63, wave = tid >> 6;
  const int l15 = lane & 15, g = (lane >> 4) & 3;
  // swizzle: id = by*8+bx; give each XCD 8 whole heads (KV L2-resident)
  const int id = blockIdx.y * 8 + blockIdx.x;
  const int xcd = id & 7, slot = id >> 3;
  const int z = xcd * 8 + (slot >> 3), b = z >> 4, h = z & 15;
  const int m0 = (slot & 7) * 128;
  const int r0 = wave * 32;

  bf16x8 qf[2][2];
  {
    const u16* qz = qh + ((size_t)z * 1024 + m0 + r0 + l15) * 64 + g * 8;
#pragma unroll
    for (int i2 = 0; i2 < 2; ++i2)
#pragma unroll
      for (int kc = 0; kc < 2; ++kc)
        qf[i2][kc] = *(const bf16x8*)(qz + (size_t)i2 * 16 * 64 + kc * 32);
  }

  float m_i[2][4], l_i[2][4];
#pragma unroll
  for (int i2 = 0; i2 < 2; ++i2)
#pragma unroll
    for (int r = 0; r < 4; ++r) { m_i[i2][r] = -1.0e30f; l_i[i2][r] = 0.0f; }

  f32x4 o[2][4] = {};
  const int tmax = causal ? m0 : 896;

  for (int t0 = 0; t0 <= tmax; t0 += 128) {
    const u16* ktile = kt + ((size_t)z * 8 + (t0 >> 7)) * 8192;
    const u16* vtile = vt + ((size_t)z * 8 + (t0 >> 7)) * 8192;
    __syncthreads();
#pragma unroll
    for (int i = 0; i < 4; ++i) {
      const int off = (wave * 4 + i) * 512 + lane * 8;
      gld16(ktile + off, sK + off);
      gld16(vtile + off, sV + off);
    }
    __syncthreads();

#pragma unroll
    for (int ci = 0; ci < 2; ++ci) {
      if (causal && t0 == m0 && ci * 64 > r0 + 31) continue;

      f32x4 sa[2][4] = {};
#pragma unroll
      for (int kc = 0; kc < 2; ++kc) {
        bf16x8 bg[4];
#pragma unroll
        for (int jn = 0; jn < 4; ++jn)
          bg[jn] = *(const bf16x8*)(sK + ((kc * 4 + g) * 128 + ci * 64 + jn * 16 + l15) * 8);
#pragma unroll
        for (int i2 = 0; i2 < 2; ++i2)
#pragma unroll
          for (int jn = 0; jn < 4; ++jn)
            sa[i2][jn] = __builtin_amdgcn_mfma_f32_16x16x32_bf16(qf[i2][kc], bg[jn], sa[i2][jn], 0, 0, 0);
      }

      if (causal) {
        if (t0 == m0 && ci * 64 + 63 > r0) {
#pragma unroll
          for (int i2 = 0; i2 < 2; ++i2)
#pragma unroll
            for (int jn = 0; jn < 4; ++jn) {
              const int col = ci * 64 + jn * 16 + l15;
#pragma unroll
              for (int r = 0; r < 4; ++r) {
                const int row = r0 + i2 * 16 + g * 4 + r;
                if (col > row) sa[i2][jn][r] = -3.0e38f;
              }
            }
        }
      } else {
#pragma unroll
        for (int jn = 0; jn < 4; ++jn) {
          const float mv = emask[(size_t)b * 1024 + t0 + ci * 64 + jn * 16 + l15];
#pragma unroll
          for (int i2 = 0; i2 < 2; ++i2)
#pragma unroll
            for (int r = 0; r < 4; ++r) sa[i2][jn][r] += mv;
        }
      }

      float alpha[2][4];
#pragma unroll
      for (int i2 = 0; i2 < 2; ++i2)
#pragma unroll
        for (int r = 0; r < 4; ++r) {
          const int rowl = r0 + i2 * 16 + g * 4 + r;
          float v = fmaxf(fmaxf(sa[i2][0][r], sa[i2][1][r]), fmaxf(sa[i2][2][r], sa[i2][3][r]));
          v = fmaxf(v, __shfl_xor(v, 1, 64));
          v = fmaxf(v, __shfl_xor(v, 2, 64));
          v = fmaxf(v, __shfl_xor(v, 4, 64));
          v = fmaxf(v, __shfl_xor(v, 8, 64));
          const float mo = m_i[i2][r];
          const float mn = fmaxf(mo, v);
          m_i[i2][r] = mn;
          alpha[i2][r] = __expf(mo - mn);
          float s = 0.0f;
#pragma unroll
          for (int jn = 0; jn < 4; ++jn) {
            const float p = __expf(sa[i2][jn][r] - mn);
            s += p;
            sP[rowl * 72 + jn * 16 + l15] = f2bf(p);
          }
          s += __shfl_xor(s, 1, 64);
          s += __shfl_xor(s, 2, 64);
          s += __shfl_xor(s, 4, 64);
          s += __shfl_xor(s, 8, 64);
          l_i[i2][r] = alpha[i2][r] * l_i[i2][r] + s;
        }

#pragma unroll
      for (int i2 = 0; i2 < 2; ++i2)
#pragma unroll
        for (int jn = 0; jn < 4; ++jn)
#pragma unroll
          for (int r = 0; r < 4; ++r)
            o[i2][jn][r] *= alpha[i2][r];

      asm volatile("s_waitcnt lgkmcnt(0)" ::: "memory");
#pragma unroll
      for (int kc2 = 0; kc2 < 2; ++kc2) {
        bf16x8 pa[2], vb[4];
#pragma unroll
        for (int i2 = 0; i2 < 2; ++i2)
          pa[i2] = *(const bf16x8*)(sP + (r0 + i2 * 16 + l15) * 72 + kc2 * 32 + g * 8);
#pragma unroll
        for (int jn = 0; jn < 4; ++jn)
          vb[jn] = *(const bf16x8*)(sV + ((ci * 8 + kc2 * 4 + g) * 64 + jn * 16 + l15) * 8);
#pragma unroll
        for (int i2 = 0; i2 < 2; ++i2)
#pragma unroll
          for (int jn = 0; jn < 4; ++jn)
            o[i2][jn] = __builtin_amdgcn_mfma_f32_16x16x32_bf16(pa[i2], vb[jn], o[i2][jn], 0, 0, 0);
      }
    }
  }

#pragma unroll
  for (int i2 = 0; i2 < 2; ++i2)
#pragma unroll
    for (int r = 0; r < 4; ++r) {
      const float inv = 1.0f / l_i[i2][r];
      const size_t base = ((size_t)(b * 1024 + m0 + r0 + i2 * 16 + g * 4 + r)) * 1024 + h * 64;
#pragma unroll
      for (int jn = 0; jn < 4; ++jn)
        ctx[base + jn * 16 + l15] = f2bf(o[i2][jn][r] * inv);
    }
}

// ---------- mega prep: 7 weight transposes + enc cvt + LN1 in one launch ----------
struct PrepArgs {
  const float* w[7]; u16* wt[7]; int K[7]; int N[7]; int cum[7];
  const float* enc; u16* enc_bf;
  const float* hid; const float* ln1w; const float* ln1b; u16* xln;
};
__global__ __launch_bounds__(256) void prep_kernel(PrepArgs a) {
  __shared__ float t[32][33];
  __shared__ float sbuf[4];
  const int bb = blockIdx.x, tid = threadIdx.x;
  if (bb < 16384) {
    int wi = 0;
#pragma unroll
    for (int i = 0; i < 7; ++i) if (bb >= a.cum[i]) wi = i + 1; else break;
    const int base = wi ? a.cum[wi - 1] : 0;
    const int tileIdx = bb - base;
    const int Kd = a.K[wi], Nd = a.N[wi], nx = Nd >> 5;
    const int n0 = (tileIdx % nx) * 32, k0 = (tileIdx / nx) * 32;
    const float* w = a.w[wi]; u16* wt = a.wt[wi];
    const int tx = tid & 31, ty = tid >> 5;
#pragma unroll
    for (int r = ty; r < 32; r += 8) t[r][tx] = w[(size_t)(k0 + r) * Nd + n0 + tx];
    __syncthreads();
#pragma unroll
    for (int r = ty; r < 32; r += 8) wt[(size_t)(n0 + r) * Kd + k0 + tx] = f2bf(t[tx][r]);
  } else if (bb < 20480) {
    const size_t i = ((size_t)(bb - 16384) * 256 + tid) * 4;
    const float4 v = *(const float4*)(a.enc + i);
    ushort4 o; o.x = f2bf(v.x); o.y = f2bf(v.y); o.z = f2bf(v.z); o.w = f2bf(v.w);
    *(ushort4*)(a.enc_bf + i) = o;
  } else {
    const int row = bb - 20480;
    const float4 v = *(const float4*)(a.hid + (size_t)row * 1024 + tid * 4);
    float s = block_sum(v.x + v.y + v.z + v.w, sbuf, tid);
    const float u = s * (1.0f / 1024.0f);
    const float d0 = v.x - u, d1 = v.y - u, d2 = v.z - u, d3 = v.w - u;
    float sq = block_sum(d0 * d0 + d1 * d1 + d2 * d2 + d3 * d3, sbuf, tid);
    const float rstd = rsqrtf(sq * (1.0f / 1024.0f) + 1e-12f);
    const int c = tid * 4;
    ushort4 o;
    o.x = f2bf(a.ln1w[c + 0] * d0 * rstd + a.ln1b[c + 0]);
    o.y = f2bf(a.ln1w[c + 1] * d1 * rstd + a.ln1b[c + 1]);
    o.z = f2bf(a.ln1w[c + 2] * d2 * rstd + a.ln1b[c + 2]);
    o.w = f2bf(a.ln1w[c + 3] * d3 * rstd + a.ln1b[c + 3]);
    *(ushort4*)(a.xln + (size_t)row * 1024 + c) = o;
  }
}

// ---------- 2-way reducers (R5, proven) ----------
__global__ __launch_bounds__(256) void ln_red_kernel(
    const float* __restrict__ p0, const float* __restrict__ p1,
    const float* __restrict__ bias, const float* __restrict__ res,
    const float* __restrict__ w, const float* __restrict__ b,
    float* __restrict__ hOut, u16* __restrict__ xln)
{
  __shared__ float sbuf[4];
  const int row = blockIdx.x, tid = threadIdx.x;
  const size_t off = (size_t)row * 1024 + tid * 4;
  const int c = tid * 4;
  const float4 a0 = *(const float4*)(p0 + off);
  const float4 a1 = *(const float4*)(p1 + off);
  const float4 bs = *(const float4*)(bias + c);
  const float4 rs = *(const float4*)(res + off);
  float4 v;
  v.x = a0.x + a1.x + bs.x + rs.x;
  v.y = a0.y + a1.y + bs.y + rs.y;
  v.z = a0.z + a1.z + bs.z + rs.z;
  v.w = a0.w + a1.w + bs.w + rs.w;
  *(float4*)(hOut + off) = v;
  float s = block_sum(v.x + v.y + v.z + v.w, sbuf, tid);
  const float u = s * (1.0f / 1024.0f);
  const float d0 = v.x - u, d1 = v.y - u, d2 = v.z - u, d3 = v.w - u;
  float sq = block_sum(d0 * d0 + d1 * d1 + d2 * d2 + d3 * d3, sbuf, tid);
  const float rstd = rsqrtf(sq * (1.0f / 1024.0f) + 1e-12f);
  ushort4 o;
  o.x = f2bf(w[c + 0] * d0 * rstd + b[c + 0]);
  o.y = f2bf(w[c + 1] * d1 * rstd + b[c + 1]);
  o.z = f2bf(w[c + 2] * d2 * rstd + b[c + 2]);
  o.w = f2bf(w[c + 3] * d3 * rstd + b[c + 3]);
  *(ushort4*)(xln + off) = o;
}

__global__ __launch_bounds__(256) void reduce_q_kernel(
    const float* __restrict__ p0, const float* __restrict__ p1,
    const float* __restrict__ bias, u16* __restrict__ qh)
{
  const int m = blockIdx.x, tid = threadIdx.x;
  const size_t off = (size_t)m * 1024 + tid * 4;
  const int n = tid * 4, h = n >> 6, d = n & 63;
  const int b = m >> 10, s = m & 1023;
  const float4 a0 = *(const float4*)(p0 + off);
  const float4 a1 = *(const float4*)(p1 + off);
  const float4 bs = *(const float4*)(bias + n);
  ushort4 o;
  o.x = f2bf((a0.x + a1.x + bs.x) * 0.125f);
  o.y = f2bf((a0.y + a1.y + bs.y) * 0.125f);
  o.z = f2bf((a0.z + a1.z + bs.z) * 0.125f);
  o.w = f2bf((a0.w + a1.w + bs.w) * 0.125f);
  *(ushort4*)(qh + ((size_t)((b * 16 + h) * 1024 + s)) * 64 + d) = o;
}

__global__ __launch_bounds__(256) void reduce_out_kernel(
    const float* __restrict__ p0, const float* __restrict__ p1,
    const float* __restrict__ bias, const float* __restrict__ res,
    float* __restrict__ out)
{
  const int m = blockIdx.x, tid = threadIdx.x;
  const size_t off = (size_t)m * 1024 + tid * 4;
  const int c = tid * 4;
  const float4 a0 = *(const float4*)(p0 + off);
  const float4 a1 = *(const float4*)(p1 + off);
  const float4 bs = *(const float4*)(bias + c);
  const float4 rs = *(const float4*)(res + off);
  float4 v;
  v.x = a0.x + a1.x + bs.x + rs.x;
  v.y = a0.y + a1.y + bs.y + rs.y;
  v.z = a0.z + a1.z + bs.z + rs.z;
  v.w = a0.w + a1.w + bs.w + rs.w;
  *(float4*)(out + off) = v;
}

// ---------- workspace layout (bytes) ----------
constexpr size_t MB = 1024ULL * 1024;
constexpr size_t WT_QKV    = 0;            // 6 MB
constexpr size_t WT_ATTN_O = 6 * MB;       // 2
constexpr size_t WT_Q      = 8 * MB;       // 2
constexpr size_t WT_KV     = 10 * MB;      // 4
constexpr size_t WT_CA_O   = 14 * MB;      // 2
constexpr size_t WT_FFN_IN = 16 * MB;      // 8
constexpr size_t WT_FFN_OUT= 24 * MB;      // 8
constexpr size_t ENC_BF    = 32 * MB;      // 8
constexpr size_t XLN       = 40 * MB;      // 8
constexpr size_t QH        = 48 * MB;      // 8
constexpr size_t KT        = 56 * MB;      // 8
constexpr size_t VT        = 64 * MB;      // 8
constexpr size_t CTX       = 72 * MB;      // 8
constexpr size_t HBUF      = 80 * MB;      // 16 (fp32 residual spine)
constexpr size_t SP0       = 96 * MB;      // 16 fp32 partial 0
constexpr size_t SP1       = 112 * MB;     // 16 fp32 partial 1
constexpr size_t FFN_MID   = 128 * MB;     // 32 bf16 [4096,4096]
// total 160 MB

extern "C" void kernel_launch(void* const* d_in, const int* in_sizes, int n_in,
                              void* d_out, int out_size, void* d_ws, size_t ws_size,
                              hipStream_t stream) {
  const float* hidden   = (const float*)d_in[0];
  const float* enc      = (const float*)d_in[1];
  const float* encm     = (const float*)d_in[2];
  const float* ln1w = (const float*)d_in[4],  *ln1b = (const float*)d_in[5];
  const float* qkv_w = (const float*)d_in[6], *qkv_b = (const float*)d_in[7];
  const float* attn_o_w = (const float*)d_in[8], *attn_o_b = (const float*)d_in[9];
  const float* ln2w = (const float*)d_in[10], *ln2b = (const float*)d_in[11];
  const float* q_w = (const float*)d_in[12],  *q_b = (const float*)d_in[13];
  const float* kv_w = (const float*)d_in[14], *kv_b = (const float*)d_in[15];
  const float* ca_o_w = (const float*)d_in[16], *ca_o_b = (const float*)d_in[17];
  const float* ln3w = (const float*)d_in[18], *ln3b = (const float*)d_in[19];
  const float* ffn_in_w = (const float*)d_in[20], *ffn_in_b = (const float*)d_in[21];
  const float* ffn_out_w = (const float*)d_in[22], *ffn_out_b = (const float*)d_in[23];

  char* ws = (char*)d_ws;
  u16* wt_qkv    = (u16*)(ws + WT_QKV);
  u16* wt_attn_o = (u16*)(ws + WT_ATTN_O);
  u16* wt_q      = (u16*)(ws + WT_Q);
  u16* wt_kv     = (u16*)(ws + WT_KV);
  u16* wt_ca_o   = (u16*)(ws + WT_CA_O);
  u16* wt_ffn_in = (u16*)(ws + WT_FFN_IN);
  u16* wt_ffn_out= (u16*)(ws + WT_FFN_OUT);
  u16* enc_bf = (u16*)(ws + ENC_BF);
  u16* xln    = (u16*)(ws + XLN);
  u16* qh     = (u16*)(ws + QH);
  u16* kt     = (u16*)(ws + KT);
  u16* vt     = (u16*)(ws + VT);
  u16* ctx    = (u16*)(ws + CTX);
  float* hF   = (float*)(ws + HBUF);
  float* sp0  = (float*)(ws + SP0);
  float* sp1  = (float*)(ws + SP1);
  u16* ffn_mid = (u16*)(ws + FFN_MID);

  // ---- prep: all weight transposes + enc cvt + LN1, one launch ----
  PrepArgs pa;
  pa.w[0] = qkv_w;    pa.wt[0] = wt_qkv;     pa.K[0] = 1024; pa.N[0] = 3072; pa.cum[0] = 3072;
  pa.w[1] = attn_o_w; pa.wt[1] = wt_attn_o;  pa.K[1] = 1024; pa.N[1] = 1024; pa.cum[1] = 4096;
  pa.w[2] = q_w;      pa.wt[2] = wt_q;       pa.K[2] = 1024; pa.N[2] = 1024; pa.cum[2] = 5120;
  pa.w[3] = kv_w;     pa.wt[3] = wt_kv;      pa.K[3] = 1024; pa.N[3] = 2048; pa.cum[3] = 7168;
  pa.w[4] = ca_o_w;   pa.wt[4] = wt_ca_o;    pa.K[4] = 1024; pa.N[4] = 1024; pa.cum[4] = 8192;
  pa.w[5] = ffn_in_w; pa.wt[5] = wt_ffn_in;  pa.K[5] = 1024; pa.N[5] = 4096; pa.cum[5] = 12288;
  pa.w[6] = ffn_out_w;pa.wt[6] = wt_ffn_out; pa.K[6] = 4096; pa.N[6] = 1024; pa.cum[6] = 16384;
  pa.enc = enc; pa.enc_bf = enc_bf;
  pa.hid = hidden; pa.ln1w = ln1w; pa.ln1b = ln1b; pa.xln = xln;
  prep_kernel<<<24576, 256, 0, stream>>>(pa);

  // ---- self-attention ----
  gemm_qkv<<<dim3(24, 32), 256, 0, stream>>>(xln, wt_qkv, qkv_b, qh, kt, vt, 1024, 1);
  flash_attn<<<dim3(8, 64), 256, 0, stream>>>(qh, kt, vt, nullptr, ctx, 1);
  gemm_splitk<<<dim3(8, 32, 2), 256, 0, stream>>>(ctx, wt_attn_o, sp0, 1024, 512);
  ln_red_kernel<<<4096, 256, 0, stream>>>(sp0, sp1, attn_o_b, hidden, ln2w, ln2b, hF, xln);

  // ---- cross-attention ----
  gemm_splitk<<<dim3(8, 32, 2), 256, 0, stream>>>(xln, wt_q, sp0, 1024, 512);
  reduce_q_kernel<<<4096, 256, 0, stream>>>(sp0, sp1, q_b, qh);
  gemm_qkv<<<dim3(16, 32), 256, 0, stream>>>(enc_bf, wt_kv, kv_b, nullptr, kt, vt, 1024, 3);
  flash_attn<<<dim3(8, 64), 256, 0, stream>>>(qh, kt, vt, encm, ctx, 0);
  gemm_splitk<<<dim3(8, 32, 2), 256, 0, stream>>>(ctx, wt_ca_o, sp0, 1024, 512);
  ln_red_kernel<<<4096, 256, 0, stream>>>(sp0, sp1, ca_o_b, hF, ln3w, ln3b, hF, xln);

  // ---- FFN ----
  gemm_gelu<<<dim3(32, 32), 256, 0, stream>>>(xln, wt_ffn_in, ffn_in_b, ffn_mid, 4096, 1024);
  gemm_splitk<<<dim3(8, 32, 2), 256, 0, stream>>>(ffn_mid, wt_ffn_out, sp0, 4096, 2048);
  reduce_out_kernel<<<4096, 256, 0, stream>>>(sp0, sp1, ffn_out_b, hF, (float*)d_out);
}

// Round 8
// 599.111 us; speedup vs baseline: 1.1579x; 1.0064x over previous
//
#include <hip/hip_runtime.h>
#include <cstdint>
#include <cstddef>

typedef unsigned short u16;
typedef __bf16 bf16x8 __attribute__((ext_vector_type(8)));
typedef float f32x4 __attribute__((ext_vector_type(4)));

// ---------- helpers ----------
__device__ __forceinline__ u16 f2bf(float f) {            // round-to-nearest-even
  unsigned u = __float_as_uint(f);
  u += 0x7fffu + ((u >> 16) & 1u);
  return (u16)(u >> 16);
}

__device__ __forceinline__ float block_sum(float v, float* sbuf, int tid) {
#pragma unroll
  for (int off = 1; off < 64; off <<= 1) v += __shfl_xor(v, off, 64);
  if ((tid & 63) == 0) sbuf[tid >> 6] = v;
  __syncthreads();
  v = sbuf[0] + sbuf[1] + sbuf[2] + sbuf[3];
  __syncthreads();
  return v;
}

// async global->LDS, 16B per lane; LDS dest = wave-uniform base + lane*16.
__device__ __forceinline__ void gld16(const void* g, void* l) {
  __builtin_amdgcn_global_load_lds((const __attribute__((address_space(1))) void*)g,
                                   (__attribute__((address_space(3))) void*)l,
                                   16, 0, 0);
}

// XCD-aware tile swizzle (requires gridDim.x % 8 == 0).
__device__ __forceinline__ void swz(int& bx, int& by) {
  const int gx = gridDim.x, gy = gridDim.y;
  const int id = blockIdx.y * gx + blockIdx.x;
  const int xcd = id & 7, slot = id >> 3;
  bx = xcd * (gx >> 3) + slot / gy;
  by = slot % gy;
}

// Tiled K layout: kt[z][tile][c=d/8][t=0..127][j=d%8]  (16KB/tile, MFMA B-frag image)
// Tiled V layout: vt[z][tile][tc=t/8][d=0..63][j=t%8]  (16KB/tile)

// ---------- double-buffered GEMM K-loop (128x128 tile, BK=32) ----------
// AITER-style: next tile's gld16 issued before waiting current (vmcnt(4) keeps
// 4 loads in flight across both barriers); raw s_barrier avoids the compiler's
// vmcnt(0) drain. No prefetch registers -> no spill (R3 lesson).
#define GEMM_SETUP(Kdim)                                                         \
  const int lane = tid & 63, wave = tid >> 6;                                    \
  const int l15 = lane & 15, g = (lane >> 4) & 3;                                \
  const int wm = (wave >> 1) * 64, wn = (wave & 1) * 64;                         \
  const int c0 = tid, c1 = tid + 256;                                            \
  const int ar0 = c0 >> 2, ak0 = (c0 & 3) * 8;                                   \
  const int ar1 = c1 >> 2, ak1 = (c1 & 3) * 8;                                   \
  const size_t aoff0 = (size_t)(m0 + ar0) * Kdim + ak0;                          \
  const size_t aoff1 = (size_t)(m0 + ar1) * Kdim + ak1;                          \
  const size_t boff0 = (size_t)(n0 + ar0) * Kdim + ak0;                          \
  const size_t boff1 = (size_t)(n0 + ar1) * Kdim + ak1;

#define GEMM_STAGE(Aptr, Bptr, kk, buf)                                          \
    gld16(Aptr + aoff0 + (kk), As + (buf) * 4096 + (size_t)c0 * 8);              \
    gld16(Aptr + aoff1 + (kk), As + (buf) * 4096 + (size_t)c1 * 8);              \
    gld16(Bptr + boff0 + (kk), Bs + (buf) * 4096 + (size_t)c0 * 8);              \
    gld16(Bptr + boff1 + (kk), Bs + (buf) * 4096 + (size_t)c1 * 8);

#define GEMM_COMPUTE(buf)                                                        \
    { bf16x8 af[4], bg[4];                                                       \
      _Pragma("unroll")                                                          \
      for (int i = 0; i < 4; i++) {                                              \
        af[i] = *(const bf16x8*)(As + (buf) * 4096 + (wm + i * 16 + l15) * 32 + g * 8); \
        bg[i] = *(const bf16x8*)(Bs + (buf) * 4096 + (wn + i * 16 + l15) * 32 + g * 8); \
      }                                                                          \
      _Pragma("unroll")                                                          \
      for (int i = 0; i < 4; i++)                                                \
        _Pragma("unroll")                                                        \
        for (int j = 0; j < 4; j++)                                              \
          acc[i][j] = __builtin_amdgcn_mfma_f32_16x16x32_bf16(af[i], bg[j], acc[i][j], 0, 0, 0); }

#define GEMM_BODY_DB(Aptr, Bptr, Kdim)                                           \
  GEMM_SETUP(Kdim)                                                               \
  f32x4 acc[4][4] = {};                                                          \
  GEMM_STAGE(Aptr, Bptr, kstart, 0)                                              \
  int cur = 0;                                                                   \
  for (int k0 = kstart; k0 + 32 < kend; k0 += 32) {                              \
    GEMM_STAGE(Aptr, Bptr, k0 + 32, cur ^ 1)                                     \
    asm volatile("s_waitcnt vmcnt(4)\ns_barrier" ::: "memory");                  \
    GEMM_COMPUTE(cur)                                                            \
    asm volatile("s_waitcnt lgkmcnt(0)\ns_barrier" ::: "memory");                \
    cur ^= 1;                                                                    \
  }                                                                              \
  asm volatile("s_waitcnt vmcnt(0)\ns_barrier" ::: "memory");                    \
  GEMM_COMPUTE(cur)

// ---------- GELU GEMM (M=4096) ----------
__global__ __launch_bounds__(256) void gemm_gelu(
    const u16* __restrict__ A, const u16* __restrict__ B,
    const float* __restrict__ bias, u16* __restrict__ out, int N, int K)
{
  __shared__ __align__(16) u16 As[2 * 128 * 32];
  __shared__ __align__(16) u16 Bs[2 * 128 * 32];
  const int tid = threadIdx.x;
  int bx, by; swz(bx, by);
  const int m0 = by * 128, n0 = bx * 128;
  const int kstart = 0, kend = K;
  GEMM_BODY_DB(A, B, K)

#pragma unroll
  for (int i = 0; i < 4; i++) {
#pragma unroll
    for (int j = 0; j < 4; j++) {
      const int col = n0 + wn + j * 16 + l15;
#pragma unroll
      for (int r = 0; r < 4; r++) {
        const int gm = m0 + wm + i * 16 + g * 4 + r;
        float v = acc[i][j][r] + bias[col];
        v = 0.5f * v * (1.0f + erff(v * 0.70710678118654752f));
        out[(size_t)gm * N + col] = f2bf(v);
      }
    }
  }
}

// ---------- QKV / KV GEMM (direct head-split tiled epilogues; M=4096) ----------
__global__ __launch_bounds__(256) void gemm_qkv(
    const u16* __restrict__ A, const u16* __restrict__ B,
    const float* __restrict__ bias,
    u16* __restrict__ qh, u16* __restrict__ kt, u16* __restrict__ vt,
    int K, int mode)
{
  __shared__ __align__(16) u16 As[2 * 128 * 32];
  __shared__ __align__(16) u16 Bs[2 * 128 * 32];
  const int tid = threadIdx.x;
  int bx, by; swz(bx, by);
  const int m0 = by * 128, n0 = bx * 128;
  const int kstart = 0, kend = K;
  GEMM_BODY_DB(A, B, K)

#pragma unroll
  for (int i = 0; i < 4; i++) {
#pragma unroll
    for (int j = 0; j < 4; j++) {
      const int col = n0 + wn + j * 16 + l15;
      const int sec = (n0 + wn + j * 16) >> 10;          // wave-uniform section
      const int tgt = (mode == 1) ? sec : sec + 1;
#pragma unroll
      for (int r = 0; r < 4; r++) {
        const int gm = m0 + wm + i * 16 + g * 4 + r;
        const float v = acc[i][j][r] + bias[col];
        const int cl = col & 1023, h = cl >> 6, d = cl & 63;
        const int z = (gm >> 10) * 16 + h, s = gm & 1023;
        if (tgt == 0)
          qh[((size_t)z * 1024 + s) * 64 + d] = f2bf(v * 0.125f);
        else if (tgt == 1)
          kt[((((size_t)z * 8 + (s >> 7)) * 8 + (d >> 3)) * 128 + (s & 127)) * 8 + (d & 7)] = f2bf(v);
        else
          vt[((size_t)z * 8 + (s >> 7)) * 8192 + (((s >> 3) & 15) * 64 + d) * 8 + (s & 7)] = f2bf(v);
      }
    }
  }
}

// ---------- split-K NT GEMM (M=4096, N=1024; fp32 partials [z][4096][1024]) ----------
__global__ __launch_bounds__(256) void gemm_splitk(
    const u16* __restrict__ A, const u16* __restrict__ B,
    float* __restrict__ part, int K, int Klen)
{
  __shared__ __align__(16) u16 As[2 * 128 * 32];
  __shared__ __align__(16) u16 Bs[2 * 128 * 32];
  const int tid = threadIdx.x;
  int bx, by; swz(bx, by);
  const int m0 = by * 128, n0 = bx * 128;
  const int kstart = blockIdx.z * Klen, kend = kstart + Klen;
  float* outP = part + (size_t)blockIdx.z * (4096ULL * 1024);
  GEMM_BODY_DB(A, B, K)

#pragma unroll
  for (int i = 0; i < 4; i++)
#pragma unroll
    for (int j = 0; j < 4; j++) {
      const int col = n0 + wn + j * 16 + l15;
#pragma unroll
      for (int r = 0; r < 4; r++) {
        const int gm = m0 + wm + i * 16 + g * 4 + r;
        outP[(size_t)gm * 1024 + col] = acc[i][j][r];
      }
    }
}

// ---------- flash attention v3 (proven) + head-per-XCD swizzle ----------
__global__ __launch_bounds__(256, 2) void flash_attn(
    const u16* __restrict__ qh, const u16* __restrict__ kt, const u16* __restrict__ vt,
    const float* __restrict__ emask, u16* __restrict__ ctx, int causal)
{
  __shared__ __align__(16) u16 sK[8192];
  __shared__ __align__(16) u16 sV[8192];
  __shared__ __align__(16) u16 sP[128 * 72];

  const int tid = threadIdx.x, lane = tid & 63, wave = tid >> 6;
  const int l15 = lane & 15, g = (lane >> 4) & 3;
  const int id = blockIdx.y * 8 + blockIdx.x;
  const int xcd = id & 7, slot = id >> 3;
  const int z = xcd * 8 + (slot >> 3), b = z >> 4, h = z & 15;
  const int m0 = (slot & 7) * 128;
  const int r0 = wave * 32;

  bf16x8 qf[2][2];
  {
    const u16* qz = qh + ((size_t)z * 1024 + m0 + r0 + l15) * 64 + g * 8;
#pragma unroll
    for (int i2 = 0; i2 < 2; ++i2)
#pragma unroll
      for (int kc = 0; kc < 2; ++kc)
        qf[i2][kc] = *(const bf16x8*)(qz + (size_t)i2 * 16 * 64 + kc * 32);
  }

  float m_i[2][4], l_i[2][4];
#pragma unroll
  for (int i2 = 0; i2 < 2; ++i2)
#pragma unroll
    for (int r = 0; r < 4; ++r) { m_i[i2][r] = -1.0e30f; l_i[i2][r] = 0.0f; }

  f32x4 o[2][4] = {};
  const int tmax = causal ? m0 : 896;

  for (int t0 = 0; t0 <= tmax; t0 += 128) {
    const u16* ktile = kt + ((size_t)z * 8 + (t0 >> 7)) * 8192;
    const u16* vtile = vt + ((size_t)z * 8 + (t0 >> 7)) * 8192;
    __syncthreads();
#pragma unroll
    for (int i = 0; i < 4; ++i) {
      const int off = (wave * 4 + i) * 512 + lane * 8;
      gld16(ktile + off, sK + off);
      gld16(vtile + off, sV + off);
    }
    __syncthreads();

#pragma unroll
    for (int ci = 0; ci < 2; ++ci) {
      if (causal && t0 == m0 && ci * 64 > r0 + 31) continue;

      f32x4 sa[2][4] = {};
#pragma unroll
      for (int kc = 0; kc < 2; ++kc) {
        bf16x8 bg[4];
#pragma unroll
        for (int jn = 0; jn < 4; ++jn)
          bg[jn] = *(const bf16x8*)(sK + ((kc * 4 + g) * 128 + ci * 64 + jn * 16 + l15) * 8);
#pragma unroll
        for (int i2 = 0; i2 < 2; ++i2)
#pragma unroll
          for (int jn = 0; jn < 4; ++jn)
            sa[i2][jn] = __builtin_amdgcn_mfma_f32_16x16x32_bf16(qf[i2][kc], bg[jn], sa[i2][jn], 0, 0, 0);
      }

      if (causal) {
        if (t0 == m0 && ci * 64 + 63 > r0) {
#pragma unroll
          for (int i2 = 0; i2 < 2; ++i2)
#pragma unroll
            for (int jn = 0; jn < 4; ++jn) {
              const int col = ci * 64 + jn * 16 + l15;
#pragma unroll
              for (int r = 0; r < 4; ++r) {
                const int row = r0 + i2 * 16 + g * 4 + r;
                if (col > row) sa[i2][jn][r] = -3.0e38f;
              }
            }
        }
      } else {
#pragma unroll
        for (int jn = 0; jn < 4; ++jn) {
          const float mv = emask[(size_t)b * 1024 + t0 + ci * 64 + jn * 16 + l15];
#pragma unroll
          for (int i2 = 0; i2 < 2; ++i2)
#pragma unroll
            for (int r = 0; r < 4; ++r) sa[i2][jn][r] += mv;
        }
      }

      float alpha[2][4];
#pragma unroll
      for (int i2 = 0; i2 < 2; ++i2)
#pragma unroll
        for (int r = 0; r < 4; ++r) {
          const int rowl = r0 + i2 * 16 + g * 4 + r;
          float v = fmaxf(fmaxf(sa[i2][0][r], sa[i2][1][r]), fmaxf(sa[i2][2][r], sa[i2][3][r]));
          v = fmaxf(v, __shfl_xor(v, 1, 64));
          v = fmaxf(v, __shfl_xor(v, 2, 64));
          v = fmaxf(v, __shfl_xor(v, 4, 64));
          v = fmaxf(v, __shfl_xor(v, 8, 64));
          const float mo = m_i[i2][r];
          const float mn = fmaxf(mo, v);
          m_i[i2][r] = mn;
          alpha[i2][r] = __expf(mo - mn);
          float s = 0.0f;
#pragma unroll
          for (int jn = 0; jn < 4; ++jn) {
            const float p = __expf(sa[i2][jn][r] - mn);
            s += p;
            sP[rowl * 72 + jn * 16 + l15] = f2bf(p);
          }
          s += __shfl_xor(s, 1, 64);
          s += __shfl_xor(s, 2, 64);
          s += __shfl_xor(s, 4, 64);
          s += __shfl_xor(s, 8, 64);
          l_i[i2][r] = alpha[i2][r] * l_i[i2][r] + s;
        }

#pragma unroll
      for (int i2 = 0; i2 < 2; ++i2)
#pragma unroll
        for (int jn = 0; jn < 4; ++jn)
#pragma unroll
          for (int r = 0; r < 4; ++r)
            o[i2][jn][r] *= alpha[i2][r];

      asm volatile("s_waitcnt lgkmcnt(0)" ::: "memory");
#pragma unroll
      for (int kc2 = 0; kc2 < 2; ++kc2) {
        bf16x8 pa[2], vb[4];
#pragma unroll
        for (int i2 = 0; i2 < 2; ++i2)
          pa[i2] = *(const bf16x8*)(sP + (r0 + i2 * 16 + l15) * 72 + kc2 * 32 + g * 8);
#pragma unroll
        for (int jn = 0; jn < 4; ++jn)
          vb[jn] = *(const bf16x8*)(sV + ((ci * 8 + kc2 * 4 + g) * 64 + jn * 16 + l15) * 8);
#pragma unroll
        for (int i2 = 0; i2 < 2; ++i2)
#pragma unroll
          for (int jn = 0; jn < 4; ++jn)
            o[i2][jn] = __builtin_amdgcn_mfma_f32_16x16x32_bf16(pa[i2], vb[jn], o[i2][jn], 0, 0, 0);
      }
    }
  }

#pragma unroll
  for (int i2 = 0; i2 < 2; ++i2)
#pragma unroll
    for (int r = 0; r < 4; ++r) {
      const float inv = 1.0f / l_i[i2][r];
      const size_t base = ((size_t)(b * 1024 + m0 + r0 + i2 * 16 + g * 4 + r)) * 1024 + h * 64;
#pragma unroll
      for (int jn = 0; jn < 4; ++jn)
        ctx[base + jn * 16 + l15] = f2bf(o[i2][jn][r] * inv);
    }
}

// ---------- mega prep: 7 weight transposes + enc cvt + LN1 in one launch ----------
struct PrepArgs {
  const float* w[7]; u16* wt[7]; int K[7]; int N[7]; int cum[7];
  const float* enc; u16* enc_bf;
  const float* hid; const float* ln1w; const float* ln1b; u16* xln;
};
__global__ __launch_bounds__(256) void prep_kernel(PrepArgs a) {
  __shared__ float t[32][33];
  __shared__ float sbuf[4];
  const int bb = blockIdx.x, tid = threadIdx.x;
  if (bb < 16384) {
    int wi = 0;
#pragma unroll
    for (int i = 0; i < 7; ++i) if (bb >= a.cum[i]) wi = i + 1; else break;
    const int base = wi ? a.cum[wi - 1] : 0;
    const int tileIdx = bb - base;
    const int Kd = a.K[wi], Nd = a.N[wi], nx = Nd >> 5;
    const int n0 = (tileIdx % nx) * 32, k0 = (tileIdx / nx) * 32;
    const float* w = a.w[wi]; u16* wt = a.wt[wi];
    const int tx = tid & 31, ty = tid >> 5;
#pragma unroll
    for (int r = ty; r < 32; r += 8) t[r][tx] = w[(size_t)(k0 + r) * Nd + n0 + tx];
    __syncthreads();
#pragma unroll
    for (int r = ty; r < 32; r += 8) wt[(size_t)(n0 + r) * Kd + k0 + tx] = f2bf(t[tx][r]);
  } else if (bb < 20480) {
    const size_t i = ((size_t)(bb - 16384) * 256 + tid) * 4;
    const float4 v = *(const float4*)(a.enc + i);
    ushort4 o; o.x = f2bf(v.x); o.y = f2bf(v.y); o.z = f2bf(v.z); o.w = f2bf(v.w);
    *(ushort4*)(a.enc_bf + i) = o;
  } else {
    const int row = bb - 20480;
    const float4 v = *(const float4*)(a.hid + (size_t)row * 1024 + tid * 4);
    float s = block_sum(v.x + v.y + v.z + v.w, sbuf, tid);
    const float u = s * (1.0f / 1024.0f);
    const float d0 = v.x - u, d1 = v.y - u, d2 = v.z - u, d3 = v.w - u;
    float sq = block_sum(d0 * d0 + d1 * d1 + d2 * d2 + d3 * d3, sbuf, tid);
    const float rstd = rsqrtf(sq * (1.0f / 1024.0f) + 1e-12f);
    const int c = tid * 4;
    ushort4 o;
    o.x = f2bf(a.ln1w[c + 0] * d0 * rstd + a.ln1b[c + 0]);
    o.y = f2bf(a.ln1w[c + 1] * d1 * rstd + a.ln1b[c + 1]);
    o.z = f2bf(a.ln1w[c + 2] * d2 * rstd + a.ln1b[c + 2]);
    o.w = f2bf(a.ln1w[c + 3] * d3 * rstd + a.ln1b[c + 3]);
    *(ushort4*)(a.xln + (size_t)row * 1024 + c) = o;
  }
}

// ---------- 2-way reducers ----------
__global__ __launch_bounds__(256) void ln_red_kernel(
    const float* __restrict__ p0, const float* __restrict__ p1,
    const float* __restrict__ bias, const float* __restrict__ res,
    const float* __restrict__ w, const float* __restrict__ b,
    float* __restrict__ hOut, u16* __restrict__ xln)
{
  __shared__ float sbuf[4];
  const int row = blockIdx.x, tid = threadIdx.x;
  const size_t off = (size_t)row * 1024 + tid * 4;
  const int c = tid * 4;
  const float4 a0 = *(const float4*)(p0 + off);
  const float4 a1 = *(const float4*)(p1 + off);
  const float4 bs = *(const float4*)(bias + c);
  const float4 rs = *(const float4*)(res + off);
  float4 v;
  v.x = a0.x + a1.x + bs.x + rs.x;
  v.y = a0.y + a1.y + bs.y + rs.y;
  v.z = a0.z + a1.z + bs.z + rs.z;
  v.w = a0.w + a1.w + bs.w + rs.w;
  *(float4*)(hOut + off) = v;
  float s = block_sum(v.x + v.y + v.z + v.w, sbuf, tid);
  const float u = s * (1.0f / 1024.0f);
  const float d0 = v.x - u, d1 = v.y - u, d2 = v.z - u, d3 = v.w - u;
  float sq = block_sum(d0 * d0 + d1 * d1 + d2 * d2 + d3 * d3, sbuf, tid);
  const float rstd = rsqrtf(sq * (1.0f / 1024.0f) + 1e-12f);
  ushort4 o;
  o.x = f2bf(w[c + 0] * d0 * rstd + b[c + 0]);
  o.y = f2bf(w[c + 1] * d1 * rstd + b[c + 1]);
  o.z = f2bf(w[c + 2] * d2 * rstd + b[c + 2]);
  o.w = f2bf(w[c + 3] * d3 * rstd + b[c + 3]);
  *(ushort4*)(xln + off) = o;
}

__global__ __launch_bounds__(256) void reduce_q_kernel(
    const float* __restrict__ p0, const float* __restrict__ p1,
    const float* __restrict__ bias, u16* __restrict__ qh)
{
  const int m = blockIdx.x, tid = threadIdx.x;
  const size_t off = (size_t)m * 1024 + tid * 4;
  const int n = tid * 4, h = n >> 6, d = n & 63;
  const int b = m >> 10, s = m & 1023;
  const float4 a0 = *(const float4*)(p0 + off);
  const float4 a1 = *(const float4*)(p1 + off);
  const float4 bs = *(const float4*)(bias + n);
  ushort4 o;
  o.x = f2bf((a0.x + a1.x + bs.x) * 0.125f);
  o.y = f2bf((a0.y + a1.y + bs.y) * 0.125f);
  o.z = f2bf((a0.z + a1.z + bs.z) * 0.125f);
  o.w = f2bf((a0.w + a1.w + bs.w) * 0.125f);
  *(ushort4*)(qh + ((size_t)((b * 16 + h) * 1024 + s)) * 64 + d) = o;
}

__global__ __launch_bounds__(256) void reduce_out_kernel(
    const float* __restrict__ p0, const float* __restrict__ p1,
    const float* __restrict__ bias, const float* __restrict__ res,
    float* __restrict__ out)
{
  const int m = blockIdx.x, tid = threadIdx.x;
  const size_t off = (size_t)m * 1024 + tid * 4;
  const int c = tid * 4;
  const float4 a0 = *(const float4*)(p0 + off);
  const float4 a1 = *(const float4*)(p1 + off);
  const float4 bs = *(const float4*)(bias + c);
  const float4 rs = *(const float4*)(res + off);
  float4 v;
  v.x = a0.x + a1.x + bs.x + rs.x;
  v.y = a0.y + a1.y + bs.y + rs.y;
  v.z = a0.z + a1.z + bs.z + rs.z;
  v.w = a0.w + a1.w + bs.w + rs.w;
  *(float4*)(out + off) = v;
}

// ---------- workspace layout (bytes) ----------
constexpr size_t MB = 1024ULL * 1024;
constexpr size_t WT_QKV    = 0;            // 6 MB
constexpr size_t WT_ATTN_O = 6 * MB;       // 2
constexpr size_t WT_Q      = 8 * MB;       // 2
constexpr size_t WT_KV     = 10 * MB;      // 4
constexpr size_t WT_CA_O   = 14 * MB;      // 2
constexpr size_t WT_FFN_IN = 16 * MB;      // 8
constexpr size_t WT_FFN_OUT= 24 * MB;      // 8
constexpr size_t ENC_BF    = 32 * MB;      // 8
constexpr size_t XLN       = 40 * MB;      // 8
constexpr size_t QH        = 48 * MB;      // 8
constexpr size_t KT        = 56 * MB;      // 8
constexpr size_t VT        = 64 * MB;      // 8
constexpr size_t CTX       = 72 * MB;      // 8
constexpr size_t HBUF      = 80 * MB;      // 16 (fp32 residual spine)
constexpr size_t SP0       = 96 * MB;      // 16 fp32 partial 0
constexpr size_t SP1       = 112 * MB;     // 16 fp32 partial 1
constexpr size_t FFN_MID   = 128 * MB;     // 32 bf16 [4096,4096]
// total 160 MB

extern "C" void kernel_launch(void* const* d_in, const int* in_sizes, int n_in,
                              void* d_out, int out_size, void* d_ws, size_t ws_size,
                              hipStream_t stream) {
  const float* hidden   = (const float*)d_in[0];
  const float* enc      = (const float*)d_in[1];
  const float* encm     = (const float*)d_in[2];
  const float* ln1w = (const float*)d_in[4],  *ln1b = (const float*)d_in[5];
  const float* qkv_w = (const float*)d_in[6], *qkv_b = (const float*)d_in[7];
  const float* attn_o_w = (const float*)d_in[8], *attn_o_b = (const float*)d_in[9];
  const float* ln2w = (const float*)d_in[10], *ln2b = (const float*)d_in[11];
  const float* q_w = (const float*)d_in[12],  *q_b = (const float*)d_in[13];
  const float* kv_w = (const float*)d_in[14], *kv_b = (const float*)d_in[15];
  const float* ca_o_w = (const float*)d_in[16], *ca_o_b = (const float*)d_in[17];
  const float* ln3w = (const float*)d_in[18], *ln3b = (const float*)d_in[19];
  const float* ffn_in_w = (const float*)d_in[20], *ffn_in_b = (const float*)d_in[21];
  const float* ffn_out_w = (const float*)d_in[22], *ffn_out_b = (const float*)d_in[23];

  char* ws = (char*)d_ws;
  u16* wt_qkv    = (u16*)(ws + WT_QKV);
  u16* wt_attn_o = (u16*)(ws + WT_ATTN_O);
  u16* wt_q      = (u16*)(ws + WT_Q);
  u16* wt_kv     = (u16*)(ws + WT_KV);
  u16* wt_ca_o   = (u16*)(ws + WT_CA_O);
  u16* wt_ffn_in = (u16*)(ws + WT_FFN_IN);
  u16* wt_ffn_out= (u16*)(ws + WT_FFN_OUT);
  u16* enc_bf = (u16*)(ws + ENC_BF);
  u16* xln    = (u16*)(ws + XLN);
  u16* qh     = (u16*)(ws + QH);
  u16* kt     = (u16*)(ws + KT);
  u16* vt     = (u16*)(ws + VT);
  u16* ctx    = (u16*)(ws + CTX);
  float* hF   = (float*)(ws + HBUF);
  float* sp0  = (float*)(ws + SP0);
  float* sp1  = (float*)(ws + SP1);
  u16* ffn_mid = (u16*)(ws + FFN_MID);

  // ---- prep: all weight transposes + enc cvt + LN1, one launch ----
  PrepArgs pa;
  pa.w[0] = qkv_w;    pa.wt[0] = wt_qkv;     pa.K[0] = 1024; pa.N[0] = 3072; pa.cum[0] = 3072;
  pa.w[1] = attn_o_w; pa.wt[1] = wt_attn_o;  pa.K[1] = 1024; pa.N[1] = 1024; pa.cum[1] = 4096;
  pa.w[2] = q_w;      pa.wt[2] = wt_q;       pa.K[2] = 1024; pa.N[2] = 1024; pa.cum[2] = 5120;
  pa.w[3] = kv_w;     pa.wt[3] = wt_kv;      pa.K[3] = 1024; pa.N[3] = 2048; pa.cum[3] = 7168;
  pa.w[4] = ca_o_w;   pa.wt[4] = wt_ca_o;    pa.K[4] = 1024; pa.N[4] = 1024; pa.cum[4] = 8192;
  pa.w[5] = ffn_in_w; pa.wt[5] = wt_ffn_in;  pa.K[5] = 1024; pa.N[5] = 4096; pa.cum[5] = 12288;
  pa.w[6] = ffn_out_w;pa.wt[6] = wt_ffn_out; pa.K[6] = 4096; pa.N[6] = 1024; pa.cum[6] = 16384;
  pa.enc = enc; pa.enc_bf = enc_bf;
  pa.hid = hidden; pa.ln1w = ln1w; pa.ln1b = ln1b; pa.xln = xln;
  prep_kernel<<<24576, 256, 0, stream>>>(pa);

  // ---- self-attention ----
  gemm_qkv<<<dim3(24, 32), 256, 0, stream>>>(xln, wt_qkv, qkv_b, qh, kt, vt, 1024, 1);
  flash_attn<<<dim3(8, 64), 256, 0, stream>>>(qh, kt, vt, nullptr, ctx, 1);
  gemm_splitk<<<dim3(8, 32, 2), 256, 0, stream>>>(ctx, wt_attn_o, sp0, 1024, 512);
  ln_red_kernel<<<4096, 256, 0, stream>>>(sp0, sp1, attn_o_b, hidden, ln2w, ln2b, hF, xln);

  // ---- cross-attention ----
  gemm_splitk<<<dim3(8, 32, 2), 256, 0, stream>>>(xln, wt_q, sp0, 1024, 512);
  reduce_q_kernel<<<4096, 256, 0, stream>>>(sp0, sp1, q_b, qh);
  gemm_qkv<<<dim3(16, 32), 256, 0, stream>>>(enc_bf, wt_kv, kv_b, nullptr, kt, vt, 1024, 3);
  flash_attn<<<dim3(8, 64), 256, 0, stream>>>(qh, kt, vt, encm, ctx, 0);
  gemm_splitk<<<dim3(8, 32, 2), 256, 0, stream>>>(ctx, wt_ca_o, sp0, 1024, 512);
  ln_red_kernel<<<4096, 256, 0, stream>>>(sp0, sp1, ca_o_b, hF, ln3w, ln3b, hF, xln);

  // ---- FFN ----
  gemm_gelu<<<dim3(32, 32), 256, 0, stream>>>(xln, wt_ffn_in, ffn_in_b, ffn_mid, 4096, 1024);
  gemm_splitk<<<dim3(8, 32, 2), 256, 0, stream>>>(ffn_mid, wt_ffn_out, sp0, 4096, 2048);
  reduce_out_kernel<<<4096, 256, 0, stream>>>(sp0, sp1, ffn_out_b, hF, (float*)d_out);
}